// Round 17
// baseline (122.016 us; speedup 1.0000x reference)
//
#include <hip/hip_runtime.h>
#include <stdint.h>

// TimestepPermutationQuantizer — PASSED r8-r16 with absmax 0.0. The
// arithmetic chain below is BIT-EXACT vs the harness golden — DO NOT CHANGE:
//   scale = fmaxf(mx-mn, 1e-5f) * (1.0f/15.0f)   // XLA const-div rewrite
//   base  = clip(rintf(-mn/scale), 0, 15)        // IEEE f32 div, half-even
//   q     = clip(rintf(v/scale) + base, 0, 15)   // IEEE f32 div
//   out   = (q - base) * scale
// Partition P1: group g members = {gat[g*128+k]}, gat = d_in[1];
// channel c's group = asn[c]>>7, asn = d_in[2].
//
// Perf log: r8 125.5 -> r9 118.7 -> r10 127.7 (+DS ops hurt) -> r11 104.7 ->
// r12 209.7 (spill) -> r13 135.0 (+DS ops hurt) -> r14 103.1 (DS-shuffle diet
// ~wash) -> r15 136.0 (pipeline +DS hurt) -> r16 106.5 (2x occupancy: FLAT).
// MODEL: asymmetric plateau = DS-pipe throughput knee. Adding DS ops hurts
// ~1us/op-class; latency/occupancy don't matter. Remaining big DS items:
// P3 row re-read (64 b128/row) + per-element sb b64 (~5-way conflicts).
// r17: (1) P3 reads the row from GLOBAL (same-XCD L2 hit — this CU DMA'd it
// one barrier ago); LDS row now serves ONLY the P2 gather. (2) sb table
// replicated 4x -> 16 lanes/copy -> ~2-way conflicts (free). DS per row
// drops from ~2600 to ~1300 cyc.

constexpr int C     = 4096;
constexpr int GS    = 128;
constexpr int NG    = C / GS;          // 32 groups
constexpr int BLOCK = 256;             // 4 waves; 16 subgroups of 16 lanes
constexpr int VECS  = C / 4 / BLOCK;   // 4 float4 per thread in P3
constexpr int NREP  = 4;               // sb table replicas

typedef const __attribute__((address_space(1))) uint32_t glb_u32;
typedef __attribute__((address_space(3))) uint32_t lds_u32;

template<int CTRL>
__device__ __forceinline__ float dpp_mov(float x) {
    // VALU-pipe cross-lane move (DPP), no DS usage.
    return __int_as_float(__builtin_amdgcn_update_dpp(
        0, __float_as_int(x), CTRL, 0xF, 0xF, true));
}

__global__ __launch_bounds__(BLOCK, 8) void tpq_kernel(
    const float* __restrict__ x,
    const int*   __restrict__ gat,   // d_in[1]: group g = {gat[g*128+k]}
    const int*   __restrict__ asn,   // d_in[2]: channel c -> pos asn[c]
    float*       __restrict__ out)
{
    __shared__ float  rowbuf[C];
    __shared__ float2 sbrep[NREP][NG];

    const int tid  = threadIdx.x;
    const int wave = tid >> 6;
    const int lane = tid & 63;
    const int sg   = tid >> 4;         // subgroup 0..15
    const int sl   = tid & 15;         // lane within subgroup

    const size_t r = blockIdx.x;       // one row per block

    // ---- stage row r into LDS via DMA (4 chunks per wave) ----
    #pragma unroll
    for (int i = 0; i < 4; ++i) {
        const float* g = x + r * C + i * 1024 + wave * 256 + lane * 4;
        float*       l = rowbuf + i * 1024 + wave * 256;
        __builtin_amdgcn_global_load_lds((glb_u32*)(uintptr_t)g,
                                         (lds_u32*)(uintptr_t)l, 16, 0, 0);
    }
    __syncthreads();   // DMA drained (vmcnt) + all waves see rowbuf

    // ---- P2: each 16-lane subgroup computes 2 groups ----
    #pragma unroll
    for (int gi = 0; gi < 2; ++gi) {
        const int g = sg * 2 + gi;
        // indices loaded fresh (gat is 16KB, L2-hot chip-wide; one-shot use)
        const int4* g4 = reinterpret_cast<const int4*>(gat + g * GS + sl * 8);
        const int4 ia = g4[0], ib = g4[1];
        const float a0 = rowbuf[ia.x], a1 = rowbuf[ia.y];
        const float a2 = rowbuf[ia.z], a3 = rowbuf[ia.w];
        const float a4 = rowbuf[ib.x], a5 = rowbuf[ib.y];
        const float a6 = rowbuf[ib.z], a7 = rowbuf[ib.w];
        float mx = fmaxf(fmaxf(fmaxf(a0, a1), fmaxf(a2, a3)),
                         fmaxf(fmaxf(a4, a5), fmaxf(a6, a7)));
        float mn = fminf(fminf(fminf(a0, a1), fminf(a2, a3)),
                         fminf(fminf(a4, a5), fminf(a6, a7)));
        mx = fmaxf(mx, dpp_mov<0xB1>(mx));   // quad_perm xor1
        mn = fminf(mn, dpp_mov<0xB1>(mn));
        mx = fmaxf(mx, dpp_mov<0x4E>(mx));   // quad_perm xor2
        mn = fminf(mn, dpp_mov<0x4E>(mn));
        mx = fmaxf(mx, dpp_mov<0x141>(mx));  // row_half_mirror xor4
        mn = fminf(mn, dpp_mov<0x141>(mn));
        mx = fmaxf(mx, dpp_mov<0x140>(mx));  // row_mirror xor8
        mn = fminf(mn, dpp_mov<0x140>(mn));
        if (sl == 0) {
            const float s = fmaxf(mx - mn, 1e-5f) * (1.0f / 15.0f);
            const float b = fminf(fmaxf(rintf(-mn / s), 0.0f), 15.0f);
            const float2 v = make_float2(s, b);
            #pragma unroll
            for (int cpy = 0; cpy < NREP; ++cpy) sbrep[cpy][g] = v;
        }
    }
    __syncthreads();   // sb visible

    // ---- P3: row from GLOBAL (same-XCD L2 hit), sb from replicated LDS ----
    const float2* myrep = sbrep[(tid >> 4) & (NREP - 1)];
    const float4* xr4   = reinterpret_cast<const float4*>(x + r * C);
    const int4*   as4   = reinterpret_cast<const int4*>(asn);
    float4*       or4   = reinterpret_cast<float4*>(out + r * C);
    #pragma unroll
    for (int i = 0; i < VECS; ++i) {
        const int    idx = tid + i * BLOCK;
        const int4   a   = as4[idx];           // L2-hot, one-shot
        const float4 v   = xr4[idx];           // L2-hit vmem (not DS pipe)
        float4 o;
        { const float2 p = myrep[a.x >> 7];
          o.x = (fminf(fmaxf(rintf(v.x / p.x) + p.y, 0.0f), 15.0f) - p.y) * p.x; }
        { const float2 p = myrep[a.y >> 7];
          o.y = (fminf(fmaxf(rintf(v.y / p.x) + p.y, 0.0f), 15.0f) - p.y) * p.x; }
        { const float2 p = myrep[a.z >> 7];
          o.z = (fminf(fmaxf(rintf(v.z / p.x) + p.y, 0.0f), 15.0f) - p.y) * p.x; }
        { const float2 p = myrep[a.w >> 7];
          o.w = (fminf(fmaxf(rintf(v.w / p.x) + p.y, 0.0f), 15.0f) - p.y) * p.x; }
        or4[idx] = o;
    }
}

extern "C" void kernel_launch(void* const* d_in, const int* in_sizes, int n_in,
                              void* d_out, int out_size, void* d_ws, size_t ws_size,
                              hipStream_t stream) {
    const float* x   = (const float*)d_in[0];
    const int*   gat = (const int*)d_in[1];   // perm (gather) — P1 partition
    const int*   asn = (const int*)d_in[2];   // inverse perm (assignment)
    float* out = (float*)d_out;

    const int rows = in_sizes[0] / C;         // 16384 — one block per row

    tpq_kernel<<<rows, BLOCK, 0, stream>>>(x, gat, asn, out);
}

// Round 18
// 106.226 us; speedup vs baseline: 1.1486x; 1.1486x over previous
//
#include <hip/hip_runtime.h>
#include <stdint.h>

// TimestepPermutationQuantizer — PASSED r8-r17 with absmax 0.0. The
// arithmetic chain below is BIT-EXACT vs the harness golden — DO NOT CHANGE:
//   scale = fmaxf(mx-mn, 1e-5f) * (1.0f/15.0f)   // XLA const-div rewrite
//   base  = clip(rintf(-mn/scale), 0, 15)        // IEEE f32 div, half-even
//   q     = clip(rintf(v/scale) + base, 0, 15)   // IEEE f32 div
//   out   = (q - base) * scale
// Partition P1: group g members = {gat[g*128+k]}, gat = d_in[1];
// channel c's group = asn[c]>>7, asn = d_in[2].
//
// Perf log: r8 125.5 -> r9 118.7 -> r10 127.7 (+DS) -> r11 104.7 ->
// r12 209.7 (spill) -> r13 135.0 (+DS) -> r14 103.1 -> r15 136.0 (+DS) ->
// r16 106.5 (1 row/block, 8 blk/CU) -> r17 122.0 (P3-from-global BAD: +L2/TA
// traffic + latency; sb-replication confounded).
// r18 = r16 + sb 4x replication ONLY (clean attribution of the one remaining
// big DS-conflict item: per-element random sb b64, ~5-way conflicts,
// ~960 cyc/row). 16 lanes/copy over 256B -> ~2.4-way -> ~free (m136).
// If flat again: 4 independent structures at 103-107 with no saturated pipe
// => plateau is the op's serial row-dependence; declare roofline.

constexpr int C     = 4096;
constexpr int GS    = 128;
constexpr int NG    = C / GS;          // 32 groups
constexpr int BLOCK = 256;             // 4 waves; 16 subgroups of 16 lanes
constexpr int VECS  = C / 4 / BLOCK;   // 4 float4 per thread in P3
constexpr int NREP  = 4;               // sb table replicas

typedef const __attribute__((address_space(1))) uint32_t glb_u32;
typedef __attribute__((address_space(3))) uint32_t lds_u32;

template<int CTRL>
__device__ __forceinline__ float dpp_mov(float x) {
    // VALU-pipe cross-lane move (DPP), no DS usage.
    return __int_as_float(__builtin_amdgcn_update_dpp(
        0, __float_as_int(x), CTRL, 0xF, 0xF, true));
}

__global__ __launch_bounds__(BLOCK, 8) void tpq_kernel(
    const float* __restrict__ x,
    const int*   __restrict__ gat,   // d_in[1]: group g = {gat[g*128+k]}
    const int*   __restrict__ asn,   // d_in[2]: channel c -> pos asn[c]
    float*       __restrict__ out)
{
    __shared__ float  rowbuf[C];
    __shared__ float2 sbrep[NREP][NG];

    const int tid  = threadIdx.x;
    const int wave = tid >> 6;
    const int lane = tid & 63;
    const int sg   = tid >> 4;         // subgroup 0..15
    const int sl   = tid & 15;         // lane within subgroup

    const size_t r = blockIdx.x;       // one row per block

    // ---- stage row r into LDS via DMA (4 chunks per wave) ----
    #pragma unroll
    for (int i = 0; i < 4; ++i) {
        const float* g = x + r * C + i * 1024 + wave * 256 + lane * 4;
        float*       l = rowbuf + i * 1024 + wave * 256;
        __builtin_amdgcn_global_load_lds((glb_u32*)(uintptr_t)g,
                                         (lds_u32*)(uintptr_t)l, 16, 0, 0);
    }
    __syncthreads();   // DMA drained (vmcnt) + all waves see rowbuf

    // ---- P2: each 16-lane subgroup computes 2 groups ----
    #pragma unroll
    for (int gi = 0; gi < 2; ++gi) {
        const int g = sg * 2 + gi;
        // indices loaded fresh (gat is 16KB, L1/L2-hot; one-shot use)
        const int4* g4 = reinterpret_cast<const int4*>(gat + g * GS + sl * 8);
        const int4 ia = g4[0], ib = g4[1];
        const float a0 = rowbuf[ia.x], a1 = rowbuf[ia.y];
        const float a2 = rowbuf[ia.z], a3 = rowbuf[ia.w];
        const float a4 = rowbuf[ib.x], a5 = rowbuf[ib.y];
        const float a6 = rowbuf[ib.z], a7 = rowbuf[ib.w];
        float mx = fmaxf(fmaxf(fmaxf(a0, a1), fmaxf(a2, a3)),
                         fmaxf(fmaxf(a4, a5), fmaxf(a6, a7)));
        float mn = fminf(fminf(fminf(a0, a1), fminf(a2, a3)),
                         fminf(fminf(a4, a5), fminf(a6, a7)));
        mx = fmaxf(mx, dpp_mov<0xB1>(mx));   // quad_perm xor1
        mn = fminf(mn, dpp_mov<0xB1>(mn));
        mx = fmaxf(mx, dpp_mov<0x4E>(mx));   // quad_perm xor2
        mn = fminf(mn, dpp_mov<0x4E>(mn));
        mx = fmaxf(mx, dpp_mov<0x141>(mx));  // row_half_mirror xor4
        mn = fminf(mn, dpp_mov<0x141>(mn));
        mx = fmaxf(mx, dpp_mov<0x140>(mx));  // row_mirror xor8
        mn = fminf(mn, dpp_mov<0x140>(mn));
        if (sl == 0) {
            const float s = fmaxf(mx - mn, 1e-5f) * (1.0f / 15.0f);
            const float b = fminf(fmaxf(rintf(-mn / s), 0.0f), 15.0f);
            const float2 v = make_float2(s, b);
            #pragma unroll
            for (int cpy = 0; cpy < NREP; ++cpy) sbrep[cpy][g] = v;
        }
    }
    __syncthreads();   // sb visible

    // ---- P3: row from LDS (conflict-free b128), sb from replicated LDS ----
    const float2* myrep = sbrep[(tid >> 4) & (NREP - 1)];
    const float4* rc4   = reinterpret_cast<const float4*>(rowbuf);
    const int4*   as4   = reinterpret_cast<const int4*>(asn);
    float4*       or4   = reinterpret_cast<float4*>(out + r * C);
    #pragma unroll
    for (int i = 0; i < VECS; ++i) {
        const int    idx = tid + i * BLOCK;
        const int4   a   = as4[idx];           // L1/L2-hot, one-shot
        const float4 v   = rc4[idx];           // conflict-free b128
        float4 o;
        { const float2 p = myrep[a.x >> 7];
          o.x = (fminf(fmaxf(rintf(v.x / p.x) + p.y, 0.0f), 15.0f) - p.y) * p.x; }
        { const float2 p = myrep[a.y >> 7];
          o.y = (fminf(fmaxf(rintf(v.y / p.x) + p.y, 0.0f), 15.0f) - p.y) * p.x; }
        { const float2 p = myrep[a.z >> 7];
          o.z = (fminf(fmaxf(rintf(v.z / p.x) + p.y, 0.0f), 15.0f) - p.y) * p.x; }
        { const float2 p = myrep[a.w >> 7];
          o.w = (fminf(fmaxf(rintf(v.w / p.x) + p.y, 0.0f), 15.0f) - p.y) * p.x; }
        or4[idx] = o;
    }
}

extern "C" void kernel_launch(void* const* d_in, const int* in_sizes, int n_in,
                              void* d_out, int out_size, void* d_ws, size_t ws_size,
                              hipStream_t stream) {
    const float* x   = (const float*)d_in[0];
    const int*   gat = (const int*)d_in[1];   // perm (gather) — P1 partition
    const int*   asn = (const int*)d_in[2];   // inverse perm (assignment)
    float* out = (float*)d_out;

    const int rows = in_sizes[0] / C;         // 16384 — one block per row

    tpq_kernel<<<rows, BLOCK, 0, stream>>>(x, gat, asn, out);
}